// Round 10
// baseline (134.341 us; speedup 1.0000x reference)
//
#include <hip/hip_runtime.h>
#include <math.h>

#define RSQ 0.99999500003749975f  // 1/sqrt(1+1e-5)

typedef __attribute__((ext_vector_type(8))) __bf16 bf16x8;
typedef __attribute__((ext_vector_type(4))) float f32x4;
typedef __attribute__((ext_vector_type(4))) unsigned int u32x4;
typedef __attribute__((ext_vector_type(2))) unsigned int u32x2;

__device__ __forceinline__ unsigned short bfb(float v) {
    return __builtin_bit_cast(unsigned short, (__bf16)v);
}
__device__ __forceinline__ float bff(unsigned short u) {
    unsigned int x = ((unsigned int)u) << 16;
    return __builtin_bit_cast(float, x);
}

// ---------------------------------------------------------------------------
// Kernel 1: CoordPooling (blocks 0..12287) writing TRANSPOSED ypT[b][l][c]
// bf16 + W fragment packing (72 tail blocks, two 192-col halves => LDS 17.4KB,
// 9 blocks/CU). TEMPORAL x loads seed L3 for kfinal's re-read (R8 evidence).
// ---------------------------------------------------------------------------
__global__ __launch_bounds__(256) void kpool(const float* __restrict__ x,
                                             const float* __restrict__ Wy,
                                             const float* __restrict__ Wh,
                                             const float* __restrict__ Ww,
                                             unsigned short* __restrict__ ypT,
                                             unsigned short* __restrict__ Wp) {
    __shared__ float sm[4352];
    int bid = blockIdx.x;
    int t = threadIdx.x;
    if (bid >= 12288) {
        int e = bid - 12288;
        int m = e / 24, ot = e % 24;
        const float* W = (m == 0) ? Wy : (m == 1) ? Wh : Ww;
#pragma unroll
        for (int half = 0; half < 2; ++half) {
            if (half) __syncthreads();
            // stage 16 rows x 192 cols, padded stride 196
#pragma unroll
            for (int k = 0; k < 3; ++k) {
                int idx = t + k * 256;          // 768 f32x4
                int r = idx / 48, c4 = idx % 48;
                f32x4 v = *reinterpret_cast<const f32x4*>(
                    W + (size_t)(ot * 16 + r) * 384 + half * 192 + c4 * 4);
                *reinterpret_cast<f32x4*>(&sm[r * 196 + c4 * 4]) = v;
            }
            __syncthreads();
            // pack 6 regions (cs_local 0..5) x 64 lanes
#pragma unroll
            for (int k = 0; k < 2; ++k) {
                int idx = t + k * 256;
                if (idx < 384) {
                    int cs_l = idx >> 6, j = idx & 63;
                    const float* src = &sm[(j & 15) * 196 + cs_l * 32 + (j >> 4) * 8];
                    u32x4 pk;
                    pk.x = (unsigned int)bfb(src[0]) | ((unsigned int)bfb(src[1]) << 16);
                    pk.y = (unsigned int)bfb(src[2]) | ((unsigned int)bfb(src[3]) << 16);
                    pk.z = (unsigned int)bfb(src[4]) | ((unsigned int)bfb(src[5]) << 16);
                    pk.w = (unsigned int)bfb(src[6]) | ((unsigned int)bfb(src[7]) << 16);
                    int cs = half * 6 + cs_l;
                    *reinterpret_cast<u32x4*>(
                        Wp + ((size_t)(m * 24 + ot) * 12 + cs) * 512 + j * 8) = pk;
                }
            }
        }
        return;
    }
    float* pl = sm;          // [4096] plane
    float* part = sm + 4096; // [256]
    const f32x4* xp = reinterpret_cast<const f32x4*>(x) + (size_t)bid * 1024;
    f32x4* pl4 = reinterpret_cast<f32x4*>(pl);
#pragma unroll
    for (int k = 0; k < 4; ++k) pl4[k * 256 + t] = xp[k * 256 + t];  // TEMPORAL: seed L3
    __syncthreads();
    int lane = t & 63, pt = t >> 6;
    int b = bid / 384, c = bid % 384;
    unsigned short* ypb = ypT + (size_t)b * 49152 + c;  // stride 384 per l
    float rs = 0.f;
#pragma unroll
    for (int j = 0; j < 16; ++j) {
        int w = (pt * 16 + j + lane) & 63;  // rotate to dodge stride-64 banks
        rs += pl[lane * 64 + w];
    }
    part[t] = rs;
    __syncthreads();
    if (t < 64) {
        float v = part[t] + part[t + 64] + part[t + 128] + part[t + 192];
        ypb[(size_t)t * 384] = bfb(v * 0.015625f);           // l = t (h-part)
    }
    __syncthreads();
    float cs = 0.f;
#pragma unroll
    for (int j = 0; j < 16; ++j) cs += pl[(pt * 16 + j) * 64 + lane];
    part[t] = cs;
    __syncthreads();
    if (t < 64) {
        float v = part[t] + part[t + 64] + part[t + 128] + part[t + 192];
        ypb[(size_t)(64 + t) * 384] = bfb(v * 0.015625f);    // l = 64+t (w-part)
    }
}

// ---------------------------------------------------------------------------
// Kernel 2 (pass 1): y = CBR(ypT, Wy) -> yT[b][l][c]. Barrier-free, LDS-free:
// A from packed Wp, B direct 16B loads from ypT (same pattern as kcbr2,
// which is verified). Depth-1 register prefetch.
// ---------------------------------------------------------------------------
__global__ __launch_bounds__(256, 3) void kcbr1(const unsigned short* __restrict__ ypT,
    const unsigned short* __restrict__ Wp,
    const float* __restrict__ g, const float* __restrict__ bb,
    unsigned short* __restrict__ yT) {
    int bid = blockIdx.x;
    int t = threadIdx.x;
    int ot = bid % 6, lt = (bid / 6) % 4, b = bid / 24;
    int o0 = ot * 64, l0 = lt * 32;
    int w = t >> 6, lane = t & 63;
    int li = lane & 15, hi = lane >> 4;
    const unsigned short* Asrc = Wp + (size_t)(ot * 4 + w) * 12 * 512 + lane * 8;
    const unsigned short* B0 = ypT + ((size_t)b * 128 + l0 + li) * 384 + hi * 8;
    const unsigned short* B1 = B0 + (size_t)16 * 384;

    f32x4 acc0 = {0.f, 0.f, 0.f, 0.f};
    f32x4 acc1 = {0.f, 0.f, 0.f, 0.f};
    bf16x8 av  = *reinterpret_cast<const bf16x8*>(Asrc);
    bf16x8 bv0 = *reinterpret_cast<const bf16x8*>(B0);
    bf16x8 bv1 = *reinterpret_cast<const bf16x8*>(B1);
    for (int ch = 0; ch < 12; ++ch) {
        bf16x8 avn, bv0n, bv1n;
        if (ch < 11) {
            avn  = *reinterpret_cast<const bf16x8*>(Asrc + (size_t)(ch + 1) * 512);
            bv0n = *reinterpret_cast<const bf16x8*>(B0 + (ch + 1) * 32);
            bv1n = *reinterpret_cast<const bf16x8*>(B1 + (ch + 1) * 32);
        }
        acc0 = __builtin_amdgcn_mfma_f32_16x16x32_bf16(av, bv0, acc0, 0, 0, 0);
        acc1 = __builtin_amdgcn_mfma_f32_16x16x32_bf16(av, bv1, acc1, 0, 0, 0);
        av = avn; bv0 = bv0n; bv1 = bv1n;
    }
    int oB = o0 + w * 16 + hi * 4;
    int lB = l0 + li;
    float s0 = g[oB] * RSQ, bi0 = bb[oB];
    float s1 = g[oB + 1] * RSQ, bi1 = bb[oB + 1];
    float s2 = g[oB + 2] * RSQ, bi2 = bb[oB + 2];
    float s3 = g[oB + 3] * RSQ, bi3 = bb[oB + 3];
    u32x2 p0, p1;
    p0.x = (unsigned int)bfb(fmaxf(fmaf(acc0[0], s0, bi0), 0.f)) |
           ((unsigned int)bfb(fmaxf(fmaf(acc0[1], s1, bi1), 0.f)) << 16);
    p0.y = (unsigned int)bfb(fmaxf(fmaf(acc0[2], s2, bi2), 0.f)) |
           ((unsigned int)bfb(fmaxf(fmaf(acc0[3], s3, bi3), 0.f)) << 16);
    p1.x = (unsigned int)bfb(fmaxf(fmaf(acc1[0], s0, bi0), 0.f)) |
           ((unsigned int)bfb(fmaxf(fmaf(acc1[1], s1, bi1), 0.f)) << 16);
    p1.y = (unsigned int)bfb(fmaxf(fmaf(acc1[2], s2, bi2), 0.f)) |
           ((unsigned int)bfb(fmaxf(fmaf(acc1[3], s3, bi3), 0.f)) << 16);
    *reinterpret_cast<u32x2*>(yT + ((size_t)b * 128 + lB) * 384 + oB) = p0;
    *reinterpret_cast<u32x2*>(yT + ((size_t)b * 128 + lB + 16) * 384 + oB) = p1;
}

// ---------------------------------------------------------------------------
// Kernel 3 (pass 2): xh|xw = CBR(yT, Wh/Ww), barrier-free, depth-1 prefetch.
// Blocks >= 768: SFP gate chain (coalesced u32 column sums over yT).
// ---------------------------------------------------------------------------
__global__ __launch_bounds__(256, 3) void kcbr2(const unsigned short* __restrict__ yT,
    const unsigned short* __restrict__ Wp,
    const float* __restrict__ gh, const float* __restrict__ bh,
    const float* __restrict__ gw, const float* __restrict__ bw,
    float* __restrict__ hw,
    const float* __restrict__ fc0_w, const float* __restrict__ fc0_b,
    const float* __restrict__ bn1_g, const float* __restrict__ bn1_b,
    const float* __restrict__ fc1_w, const float* __restrict__ fc1_b,
    float* __restrict__ z2) {
    int bid = blockIdx.x;
    int t = threadIdx.x;
    if (bid >= 768) {
        __shared__ float z0[384];
        __shared__ float z1[24];
        int b = bid - 768;
        const unsigned short* yb = yT + (size_t)b * 49152;
        if (t < 192) {
            int c2 = t * 2;
            float s0 = 0.f, s1 = 0.f;
#pragma unroll 8
            for (int l = 0; l < 128; ++l) {
                unsigned int v = *reinterpret_cast<const unsigned int*>(yb + (size_t)l * 384 + c2);
                s0 += bff((unsigned short)(v & 0xffff));
                s1 += bff((unsigned short)(v >> 16));
            }
            float fac = (c2 < 128) ? 1.41421356237310f : (c2 < 256 ? 2.0f : 2.82842712474619f);
            z0[c2]     = s0 * (fac * 0.0078125f);
            z0[c2 + 1] = s1 * (fac * 0.0078125f);
        }
        __syncthreads();
        if (t < 96) {
            int r = t >> 2, j = t & 3;
            float p = 0.f;
            for (int c = j; c < 384; c += 4) p = fmaf(z0[c], fc0_w[r * 384 + c], p);
            p += __shfl_xor(p, 1);
            p += __shfl_xor(p, 2);
            if (j == 0) z1[r] = fmaxf(fmaf(p + fc0_b[r], bn1_g[r] * RSQ, bn1_b[r]), 0.f);
        }
        __syncthreads();
        for (int c = t; c < 384; c += 256) {
            float a = fc1_b[c];
#pragma unroll
            for (int r = 0; r < 24; ++r) a = fmaf(z1[r], fc1_w[c * 24 + r], a);
            z2[b * 384 + c] = a;
        }
        return;
    }
    int ot = bid % 6, lt = (bid / 6) % 4, b = bid / 24;
    int o0 = ot * 64, l0 = lt * 32;
    int m = (lt >= 2) ? 2 : 1;
    const float* g  = (lt >= 2) ? gw : gh;
    const float* bb = (lt >= 2) ? bw : bh;
    int w = t >> 6, lane = t & 63;
    int li = lane & 15, hi = lane >> 4;
    const unsigned short* Asrc = Wp + (size_t)(m * 24 + ot * 4 + w) * 12 * 512 + lane * 8;
    const unsigned short* B0 = yT + ((size_t)b * 128 + l0 + li) * 384 + hi * 8;
    const unsigned short* B1 = B0 + (size_t)16 * 384;

    f32x4 acc0 = {0.f, 0.f, 0.f, 0.f};
    f32x4 acc1 = {0.f, 0.f, 0.f, 0.f};
    bf16x8 av  = *reinterpret_cast<const bf16x8*>(Asrc);
    bf16x8 bv0 = *reinterpret_cast<const bf16x8*>(B0);
    bf16x8 bv1 = *reinterpret_cast<const bf16x8*>(B1);
    for (int ch = 0; ch < 12; ++ch) {
        bf16x8 avn, bv0n, bv1n;
        if (ch < 11) {
            avn  = *reinterpret_cast<const bf16x8*>(Asrc + (size_t)(ch + 1) * 512);
            bv0n = *reinterpret_cast<const bf16x8*>(B0 + (ch + 1) * 32);
            bv1n = *reinterpret_cast<const bf16x8*>(B1 + (ch + 1) * 32);
        }
        acc0 = __builtin_amdgcn_mfma_f32_16x16x32_bf16(av, bv0, acc0, 0, 0, 0);
        acc1 = __builtin_amdgcn_mfma_f32_16x16x32_bf16(av, bv1, acc1, 0, 0, 0);
        av = avn; bv0 = bv0n; bv1 = bv1n;
    }
    int oB = o0 + w * 16 + hi * 4;
    int lB = l0 + li;
#pragma unroll
    for (int r = 0; r < 4; ++r) {
        int o = oB + r;
        float sc = g[o] * RSQ, bi = bb[o];
        size_t base = ((size_t)b * 384 + o) * 128 + lB;
        hw[base]      = fmaxf(fmaf(acc0[r], sc, bi), 0.f);
        hw[base + 16] = fmaxf(fmaf(acc1[r], sc, bi), 0.f);
    }
}

// ---------------------------------------------------------------------------
// Kernel 4: out = x * (sigmoid(xh[b,c,h]*xw[b,c,w]) + z2[b,c]).
// TEMPORAL x read (L3 hit, seeded by kpool); NONTEMPORAL out store.
// ---------------------------------------------------------------------------
__global__ __launch_bounds__(256) void kfinal(const float* __restrict__ x,
    const float* __restrict__ hw, const float* __restrict__ z2,
    float* __restrict__ out) {
    const f32x4* x4 = reinterpret_cast<const f32x4*>(x);
    f32x4* o4 = reinterpret_cast<f32x4*>(out);
    const int total4 = 12582912;  // 32*384*64*64/4
    int stride = gridDim.x * blockDim.x;
    for (int idx = blockIdx.x * blockDim.x + threadIdx.x; idx < total4; idx += stride) {
        int w4 = idx & 15;
        int h  = (idx >> 4) & 63;
        int bc = idx >> 10;
        f32x4 xv = x4[idx];  // TEMPORAL: hits L3
        float  a  = hw[(bc << 7) + h];
        const f32x4 wv = reinterpret_cast<const f32x4*>(hw)[(bc << 5) + 16 + w4];
        float  zv = z2[bc];
        f32x4 ov;
        ov.x = xv.x * (1.f / (1.f + __expf(-a * wv.x)) + zv);
        ov.y = xv.y * (1.f / (1.f + __expf(-a * wv.y)) + zv);
        ov.z = xv.z * (1.f / (1.f + __expf(-a * wv.z)) + zv);
        ov.w = xv.w * (1.f / (1.f + __expf(-a * wv.w)) + zv);
        __builtin_nontemporal_store(ov, o4 + idx);  // don't evict x
    }
}

// ---------------------------------------------------------------------------
extern "C" void kernel_launch(void* const* d_in, const int* in_sizes, int n_in,
                              void* d_out, int out_size, void* d_ws, size_t ws_size,
                              hipStream_t stream) {
    const float* x     = (const float*)d_in[0];
    const float* Wy    = (const float*)d_in[1];
    const float* gy    = (const float*)d_in[2];
    const float* by    = (const float*)d_in[3];
    const float* Wh    = (const float*)d_in[4];
    const float* gh    = (const float*)d_in[5];
    const float* bh    = (const float*)d_in[6];
    const float* Ww    = (const float*)d_in[7];
    const float* gw    = (const float*)d_in[8];
    const float* bw    = (const float*)d_in[9];
    const float* fc0_w = (const float*)d_in[10];
    const float* fc0_b = (const float*)d_in[11];
    const float* bn1_g = (const float*)d_in[12];
    const float* bn1_b = (const float*)d_in[13];
    const float* fc1_w = (const float*)d_in[14];
    const float* fc1_b = (const float*)d_in[15];
    float* out = (float*)d_out;

    char* ws = (char*)d_ws;
    unsigned short* ypT = (unsigned short*)ws;                    // [32][128][384] bf16
    unsigned short* yT  = (unsigned short*)(ws + 3145728);        // [32][128][384] bf16
    float*          hww = (float*)(ws + 6291456);                 // [32][384][128] f32
    float*          z2  = (float*)(ws + 12582912);                // [32][384] f32
    unsigned short* Wp  = (unsigned short*)(ws + 12632064);       // 3x24x12x512 bf16 packed

    kpool<<<dim3(12288 + 72), dim3(256), 0, stream>>>(x, Wy, Wh, Ww, ypT, Wp);
    kcbr1<<<dim3(768), dim3(256), 0, stream>>>(ypT, Wp, gy, by, yT);
    kcbr2<<<dim3(800), dim3(256), 0, stream>>>(yT, Wp, gh, bh, gw, bw, hww,
        fc0_w, fc0_b, bn1_g, bn1_b, fc1_w, fc1_b, z2);
    kfinal<<<dim3(2048), dim3(256), 0, stream>>>(x, hww, z2, out);
}

// Round 11
// 125.609 us; speedup vs baseline: 1.0695x; 1.0695x over previous
//
#include <hip/hip_runtime.h>
#include <math.h>

#define RSQ 0.99999500003749975f  // 1/sqrt(1+1e-5)

typedef __attribute__((ext_vector_type(8))) __bf16 bf16x8;
typedef __attribute__((ext_vector_type(4))) float f32x4;
typedef __attribute__((ext_vector_type(4))) unsigned int u32x4;
typedef __attribute__((ext_vector_type(2))) unsigned int u32x2;

__device__ __forceinline__ unsigned short bfb(float v) {
    return __builtin_bit_cast(unsigned short, (__bf16)v);
}
__device__ __forceinline__ float bff(unsigned short u) {
    unsigned int x = ((unsigned int)u) << 16;
    return __builtin_bit_cast(float, x);
}

// ---------------------------------------------------------------------------
// Kernel 1: CoordPooling (blocks 0..12287, bf16 [b][c][l] output, COALESCED
// 128-B row writes) + W fragment packing (72 tail blocks). TEMPORAL x loads
// seed L3 for kfinal's re-read (R8 FETCH=230MB evidence; R10 showed transposed
// 2-B scatter writes here cost more than they save downstream).
// ---------------------------------------------------------------------------
__global__ __launch_bounds__(256) void kpool(const float* __restrict__ x,
                                             const float* __restrict__ Wy,
                                             const float* __restrict__ Wh,
                                             const float* __restrict__ Ww,
                                             unsigned short* __restrict__ ypb,
                                             unsigned short* __restrict__ Wp) {
    __shared__ float sm[6208];
    int bid = blockIdx.x;
    int t = threadIdx.x;
    if (bid >= 12288) {
        int e = bid - 12288;
        int m = e / 24, ot = e % 24;
        const float* W = (m == 0) ? Wy : (m == 1) ? Wh : Ww;
#pragma unroll
        for (int k = 0; k < 6; ++k) {
            int idx = t + k * 256;          // 1536 float4
            int r = idx / 96, c4 = idx % 96;
            f32x4 v = *reinterpret_cast<const f32x4*>(W + (size_t)(ot * 16 + r) * 384 + c4 * 4);
            *reinterpret_cast<f32x4*>(&sm[r * 388 + c4 * 4]) = v;
        }
        __syncthreads();
#pragma unroll
        for (int k = 0; k < 3; ++k) {
            int idx = t + k * 256;          // 768 = 12 cs x 64 lanes
            int cs = idx >> 6, j = idx & 63;
            const float* src = &sm[(j & 15) * 388 + cs * 32 + (j >> 4) * 8];
            u32x4 pk;
            pk.x = (unsigned int)bfb(src[0]) | ((unsigned int)bfb(src[1]) << 16);
            pk.y = (unsigned int)bfb(src[2]) | ((unsigned int)bfb(src[3]) << 16);
            pk.z = (unsigned int)bfb(src[4]) | ((unsigned int)bfb(src[5]) << 16);
            pk.w = (unsigned int)bfb(src[6]) | ((unsigned int)bfb(src[7]) << 16);
            *reinterpret_cast<u32x4*>(Wp + ((size_t)(m * 24 + ot) * 12 + cs) * 512 + j * 8) = pk;
        }
        return;
    }
    float* pl = sm;          // [4096] plane
    float* part = sm + 4096; // [256]
    const f32x4* xp = reinterpret_cast<const f32x4*>(x) + (size_t)bid * 1024;
    f32x4* pl4 = reinterpret_cast<f32x4*>(pl);
#pragma unroll
    for (int k = 0; k < 4; ++k) pl4[k * 256 + t] = xp[k * 256 + t];  // TEMPORAL: seed L3
    __syncthreads();
    int lane = t & 63, pt = t >> 6;
    float rs = 0.f;
#pragma unroll
    for (int j = 0; j < 16; ++j) {
        int w = (pt * 16 + j + lane) & 63;  // rotate to dodge stride-64 banks
        rs += pl[lane * 64 + w];
    }
    part[t] = rs;
    __syncthreads();
    if (t < 64) {
        float v = part[t] + part[t + 64] + part[t + 128] + part[t + 192];
        ypb[(size_t)bid * 128 + t] = bfb(v * 0.015625f);
    }
    __syncthreads();
    float cs = 0.f;
#pragma unroll
    for (int j = 0; j < 16; ++j) cs += pl[(pt * 16 + j) * 64 + lane];
    part[t] = cs;
    __syncthreads();
    if (t < 64) {
        float v = part[t] + part[t + 64] + part[t + 128] + part[t + 192];
        ypb[(size_t)bid * 128 + 64 + t] = bfb(v * 0.015625f);
    }
}

// ---------------------------------------------------------------------------
// Kernel 2 (pass 1): y = CBR(yp, Wy). A direct from packed Wp; B staged in
// double-buffered LDS (BK=64, one barrier per chunk). Output TRANSPOSED:
// yT[b][l][c] bf16.
// ---------------------------------------------------------------------------
__global__ __launch_bounds__(256) void kcbr1(const unsigned short* __restrict__ yp,
    const unsigned short* __restrict__ Wp,
    const float* __restrict__ g, const float* __restrict__ bb,
    unsigned short* __restrict__ yT) {
    __shared__ unsigned short Bs[2][2048];  // [8 cg][32 l][8 ci]
    int bid = blockIdx.x;
    int t = threadIdx.x;
    int ot = bid % 6, lt = (bid / 6) % 4, b = bid / 24;
    int o0 = ot * 64, l0 = lt * 32;
    int w = t >> 6, lane = t & 63;

    int c_s0 = t >> 3, l4_0 = (t & 7) * 4;
    int c_s1 = (t + 256) >> 3;
    const unsigned short* ypbase = yp + (size_t)b * 49152 + l0;
    const unsigned short* Asrc = Wp + (size_t)(ot * 4 + w) * 12 * 512 + lane * 8;

    f32x4 acc0 = {0.f, 0.f, 0.f, 0.f};
    f32x4 acc1 = {0.f, 0.f, 0.f, 0.f};

    auto stage = [&](int buf, u32x2 r0, u32x2 r1) {
        unsigned short* B0 = &Bs[buf][(c_s0 >> 3) * 256 + l4_0 * 8 + (c_s0 & 7)];
        B0[0] = (unsigned short)(r0.x & 0xffff); B0[8] = (unsigned short)(r0.x >> 16);
        B0[16] = (unsigned short)(r0.y & 0xffff); B0[24] = (unsigned short)(r0.y >> 16);
        unsigned short* B1 = &Bs[buf][(c_s1 >> 3) * 256 + l4_0 * 8 + (c_s1 & 7)];
        B1[0] = (unsigned short)(r1.x & 0xffff); B1[8] = (unsigned short)(r1.x >> 16);
        B1[16] = (unsigned short)(r1.y & 0xffff); B1[24] = (unsigned short)(r1.y >> 16);
    };
    u32x2 r0, r1;
    r0 = *reinterpret_cast<const u32x2*>(ypbase + (size_t)c_s0 * 128 + l4_0);
    r1 = *reinterpret_cast<const u32x2*>(ypbase + (size_t)c_s1 * 128 + l4_0);
    stage(0, r0, r1);
#pragma unroll
    for (int ch = 0; ch < 6; ++ch) {
        __syncthreads();
        if (ch < 5) {
            r0 = *reinterpret_cast<const u32x2*>(ypbase + (size_t)((ch + 1) * 64 + c_s0) * 128 + l4_0);
            r1 = *reinterpret_cast<const u32x2*>(ypbase + (size_t)((ch + 1) * 64 + c_s1) * 128 + l4_0);
        }
        const unsigned short* Bb = Bs[ch & 1];
        int li = lane & 15, hi = lane >> 4;
#pragma unroll
        for (int kk = 0; kk < 2; ++kk) {
            bf16x8 av = *reinterpret_cast<const bf16x8*>(Asrc + (size_t)(ch * 2 + kk) * 512);
            int cg2 = kk * 4 + hi;
            bf16x8 bv0 = *reinterpret_cast<const bf16x8*>(&Bb[cg2 * 256 + li * 8]);
            bf16x8 bv1 = *reinterpret_cast<const bf16x8*>(&Bb[cg2 * 256 + (li + 16) * 8]);
            acc0 = __builtin_amdgcn_mfma_f32_16x16x32_bf16(av, bv0, acc0, 0, 0, 0);
            acc1 = __builtin_amdgcn_mfma_f32_16x16x32_bf16(av, bv1, acc1, 0, 0, 0);
        }
        if (ch < 5) stage((ch + 1) & 1, r0, r1);
    }
    int oB = o0 + w * 16 + (lane >> 4) * 4;
    int lB = l0 + (lane & 15);
    float s0 = g[oB] * RSQ, bi0 = bb[oB];
    float s1 = g[oB + 1] * RSQ, bi1 = bb[oB + 1];
    float s2 = g[oB + 2] * RSQ, bi2 = bb[oB + 2];
    float s3 = g[oB + 3] * RSQ, bi3 = bb[oB + 3];
    u32x2 p0, p1;
    p0.x = (unsigned int)bfb(fmaxf(fmaf(acc0[0], s0, bi0), 0.f)) |
           ((unsigned int)bfb(fmaxf(fmaf(acc0[1], s1, bi1), 0.f)) << 16);
    p0.y = (unsigned int)bfb(fmaxf(fmaf(acc0[2], s2, bi2), 0.f)) |
           ((unsigned int)bfb(fmaxf(fmaf(acc0[3], s3, bi3), 0.f)) << 16);
    p1.x = (unsigned int)bfb(fmaxf(fmaf(acc1[0], s0, bi0), 0.f)) |
           ((unsigned int)bfb(fmaxf(fmaf(acc1[1], s1, bi1), 0.f)) << 16);
    p1.y = (unsigned int)bfb(fmaxf(fmaf(acc1[2], s2, bi2), 0.f)) |
           ((unsigned int)bfb(fmaxf(fmaf(acc1[3], s3, bi3), 0.f)) << 16);
    *reinterpret_cast<u32x2*>(yT + ((size_t)b * 128 + lB) * 384 + oB) = p0;
    *reinterpret_cast<u32x2*>(yT + ((size_t)b * 128 + lB + 16) * 384 + oB) = p1;
}

// ---------------------------------------------------------------------------
// Kernel 3 (pass 2): xh|xw = CBR(yT, Wh/Ww). No LDS, no barriers; depth-1
// register prefetch. Blocks >= 768: SFP gate chain (coalesced u32 col sums).
// ---------------------------------------------------------------------------
__global__ __launch_bounds__(256, 3) void kcbr2(const unsigned short* __restrict__ yT,
    const unsigned short* __restrict__ Wp,
    const float* __restrict__ gh, const float* __restrict__ bh,
    const float* __restrict__ gw, const float* __restrict__ bw,
    float* __restrict__ hw,
    const float* __restrict__ fc0_w, const float* __restrict__ fc0_b,
    const float* __restrict__ bn1_g, const float* __restrict__ bn1_b,
    const float* __restrict__ fc1_w, const float* __restrict__ fc1_b,
    float* __restrict__ z2) {
    int bid = blockIdx.x;
    int t = threadIdx.x;
    if (bid >= 768) {
        __shared__ float z0[384];
        __shared__ float z1[24];
        int b = bid - 768;
        const unsigned short* yb = yT + (size_t)b * 49152;
        if (t < 192) {
            int c2 = t * 2;
            float s0 = 0.f, s1 = 0.f;
#pragma unroll 8
            for (int l = 0; l < 128; ++l) {
                unsigned int v = *reinterpret_cast<const unsigned int*>(yb + (size_t)l * 384 + c2);
                s0 += bff((unsigned short)(v & 0xffff));
                s1 += bff((unsigned short)(v >> 16));
            }
            float fac = (c2 < 128) ? 1.41421356237310f : (c2 < 256 ? 2.0f : 2.82842712474619f);
            z0[c2]     = s0 * (fac * 0.0078125f);
            z0[c2 + 1] = s1 * (fac * 0.0078125f);
        }
        __syncthreads();
        if (t < 96) {
            int r = t >> 2, j = t & 3;
            float p = 0.f;
            for (int c = j; c < 384; c += 4) p = fmaf(z0[c], fc0_w[r * 384 + c], p);
            p += __shfl_xor(p, 1);
            p += __shfl_xor(p, 2);
            if (j == 0) z1[r] = fmaxf(fmaf(p + fc0_b[r], bn1_g[r] * RSQ, bn1_b[r]), 0.f);
        }
        __syncthreads();
        for (int c = t; c < 384; c += 256) {
            float a = fc1_b[c];
#pragma unroll
            for (int r = 0; r < 24; ++r) a = fmaf(z1[r], fc1_w[c * 24 + r], a);
            z2[b * 384 + c] = a;
        }
        return;
    }
    int ot = bid % 6, lt = (bid / 6) % 4, b = bid / 24;
    int o0 = ot * 64, l0 = lt * 32;
    int m = (lt >= 2) ? 2 : 1;
    const float* g  = (lt >= 2) ? gw : gh;
    const float* bb = (lt >= 2) ? bw : bh;
    int w = t >> 6, lane = t & 63;
    int li = lane & 15, hi = lane >> 4;
    const unsigned short* Asrc = Wp + (size_t)(m * 24 + ot * 4 + w) * 12 * 512 + lane * 8;
    const unsigned short* B0 = yT + ((size_t)b * 128 + l0 + li) * 384 + hi * 8;
    const unsigned short* B1 = B0 + (size_t)16 * 384;

    f32x4 acc0 = {0.f, 0.f, 0.f, 0.f};
    f32x4 acc1 = {0.f, 0.f, 0.f, 0.f};
    bf16x8 av  = *reinterpret_cast<const bf16x8*>(Asrc);
    bf16x8 bv0 = *reinterpret_cast<const bf16x8*>(B0);
    bf16x8 bv1 = *reinterpret_cast<const bf16x8*>(B1);
    for (int ch = 0; ch < 12; ++ch) {
        bf16x8 avn, bv0n, bv1n;
        if (ch < 11) {
            avn  = *reinterpret_cast<const bf16x8*>(Asrc + (size_t)(ch + 1) * 512);
            bv0n = *reinterpret_cast<const bf16x8*>(B0 + (ch + 1) * 32);
            bv1n = *reinterpret_cast<const bf16x8*>(B1 + (ch + 1) * 32);
        }
        acc0 = __builtin_amdgcn_mfma_f32_16x16x32_bf16(av, bv0, acc0, 0, 0, 0);
        acc1 = __builtin_amdgcn_mfma_f32_16x16x32_bf16(av, bv1, acc1, 0, 0, 0);
        av = avn; bv0 = bv0n; bv1 = bv1n;
    }
    int oB = o0 + w * 16 + hi * 4;
    int lB = l0 + li;
#pragma unroll
    for (int r = 0; r < 4; ++r) {
        int o = oB + r;
        float sc = g[o] * RSQ, bi = bb[o];
        size_t base = ((size_t)b * 384 + o) * 128 + lB;
        hw[base]      = fmaxf(fmaf(acc0[r], sc, bi), 0.f);
        hw[base + 16] = fmaxf(fmaf(acc1[r], sc, bi), 0.f);
    }
}

// ---------------------------------------------------------------------------
// Kernel 4: out = x * (sigmoid(xh[b,c,h]*xw[b,c,w]) + z2[b,c]).
// TEMPORAL x read (L3 hit, seeded by kpool); NONTEMPORAL out store.
// Grid 4096 for extra TLP on the 402 MB stream.
// ---------------------------------------------------------------------------
__global__ __launch_bounds__(256) void kfinal(const float* __restrict__ x,
    const float* __restrict__ hw, const float* __restrict__ z2,
    float* __restrict__ out) {
    const f32x4* x4 = reinterpret_cast<const f32x4*>(x);
    f32x4* o4 = reinterpret_cast<f32x4*>(out);
    const int total4 = 12582912;  // 32*384*64*64/4
    int stride = gridDim.x * blockDim.x;
    for (int idx = blockIdx.x * blockDim.x + threadIdx.x; idx < total4; idx += stride) {
        int w4 = idx & 15;
        int h  = (idx >> 4) & 63;
        int bc = idx >> 10;
        f32x4 xv = x4[idx];  // TEMPORAL: hits L3
        float  a  = hw[(bc << 7) + h];
        const f32x4 wv = reinterpret_cast<const f32x4*>(hw)[(bc << 5) + 16 + w4];
        float  zv = z2[bc];
        f32x4 ov;
        ov.x = xv.x * (1.f / (1.f + __expf(-a * wv.x)) + zv);
        ov.y = xv.y * (1.f / (1.f + __expf(-a * wv.y)) + zv);
        ov.z = xv.z * (1.f / (1.f + __expf(-a * wv.z)) + zv);
        ov.w = xv.w * (1.f / (1.f + __expf(-a * wv.w)) + zv);
        __builtin_nontemporal_store(ov, o4 + idx);  // don't evict x
    }
}

// ---------------------------------------------------------------------------
extern "C" void kernel_launch(void* const* d_in, const int* in_sizes, int n_in,
                              void* d_out, int out_size, void* d_ws, size_t ws_size,
                              hipStream_t stream) {
    const float* x     = (const float*)d_in[0];
    const float* Wy    = (const float*)d_in[1];
    const float* gy    = (const float*)d_in[2];
    const float* by    = (const float*)d_in[3];
    const float* Wh    = (const float*)d_in[4];
    const float* gh    = (const float*)d_in[5];
    const float* bh    = (const float*)d_in[6];
    const float* Ww    = (const float*)d_in[7];
    const float* gw    = (const float*)d_in[8];
    const float* bw    = (const float*)d_in[9];
    const float* fc0_w = (const float*)d_in[10];
    const float* fc0_b = (const float*)d_in[11];
    const float* bn1_g = (const float*)d_in[12];
    const float* bn1_b = (const float*)d_in[13];
    const float* fc1_w = (const float*)d_in[14];
    const float* fc1_b = (const float*)d_in[15];
    float* out = (float*)d_out;

    char* ws = (char*)d_ws;
    unsigned short* ypb = (unsigned short*)ws;                    // [32][384][128] bf16
    unsigned short* yT  = (unsigned short*)(ws + 3145728);        // [32][128][384] bf16
    float*          hww = (float*)(ws + 6291456);                 // [32][384][128] f32
    float*          z2  = (float*)(ws + 12582912);                // [32][384] f32
    unsigned short* Wp  = (unsigned short*)(ws + 12632064);       // 3x24x12x512 bf16 packed

    kpool<<<dim3(12288 + 72), dim3(256), 0, stream>>>(x, Wy, Wh, Ww, ypb, Wp);
    kcbr1<<<dim3(768), dim3(256), 0, stream>>>(ypb, Wp, gy, by, yT);
    kcbr2<<<dim3(800), dim3(256), 0, stream>>>(yT, Wp, gh, bh, gw, bw, hww,
        fc0_w, fc0_b, bn1_g, bn1_b, fc1_w, fc1_b, z2);
    kfinal<<<dim3(4096), dim3(256), 0, stream>>>(x, hww, z2, out);
}